// Round 5
// baseline (408.419 us; speedup 1.0000x reference)
//
#include <hip/hip_runtime.h>
#include <hip/hip_bf16.h>
#include <hip/hip_fp16.h>

typedef unsigned int u32;
typedef unsigned short u16;
typedef _Float16 f16x8 __attribute__((ext_vector_type(8)));
typedef float f32x4 __attribute__((ext_vector_type(4)));

#define NBLK1 512   // pass-1 blocks (edge chunks)
#define CVTBLK 256  // X->fp16 convert blocks fused into k1

// ---------- fp16 pack helpers ----------
__device__ __forceinline__ u16 f2h(float f) { return __half_as_ushort(__float2half(f)); }
__device__ __forceinline__ u32 packh2(float a, float b) {
    return (u32)f2h(a) | ((u32)f2h(b) << 16);
}

// ---------- int-width-agnostic index load (w64=1 -> int64 data on device) ----------
__device__ __forceinline__ int gidx(const void* p, long long i, int w64) {
    if (w64) return (int)((const long long*)p)[i];
    return ((const int*)p)[i];
}

// per-block int64 detection (probe odd words; int32 data -> some nonzero, int64 -> all zero)
__device__ __forceinline__ int detect_w64(const int* edge_words, int E, int tid, int* sh) {
    if (tid == 0) *sh = 0;
    __syncthreads();
    const long long totalWords = 2LL * E;
    const long long step = totalWords / 256;
    long long w = ((long long)tid * step) | 1;
    int nz = (w < totalWords) ? edge_words[w] : 0;
    if (nz) atomicOr(sh, 1);
    __syncthreads();
    return (*sh) ? 0 : 1;
}

// ---------- fused: p1 coarse hist (blocks < NBLK1) + X -> fp16 convert (rest) ----------
__global__ void __launch_bounds__(256) fused_hist_cvt(
        const void* __restrict__ edge, int* __restrict__ flag, u32* __restrict__ ticket,
        u32* __restrict__ HG, int E, int n, int nb1,
        const float* __restrict__ X, u16* __restrict__ Xh) {
    if (blockIdx.x < NBLK1) {
        __shared__ u32 h[256];
        __shared__ int shnz;
        const int tid = threadIdx.x;
        h[tid] = 0;
        const int w64 = detect_w64((const int*)edge, E, tid, &shnz);
        if (blockIdx.x == 0 && tid == 0) { flag[0] = w64; ticket[0] = 0; }
        __syncthreads();
        const int chunk = (E + NBLK1 - 1) / NBLK1;
        const int s = blockIdx.x * chunk;
        const int e = min(s + chunk, E);
        for (int i = s + tid; i < e; i += 256) {
            int d = gidx(edge, (long long)E + i, w64);
            if ((unsigned)d >= (unsigned)n) d = 0;
            atomicAdd(&h[d >> 9], 1);
        }
        __syncthreads();
        for (int b = tid; b < nb1; b += 256) HG[b * NBLK1 + blockIdx.x] = h[b];
        return;
    }
    // elementwise convert X (fp32) -> Xh (fp16), 4 elems / thread / iter
    const long long total4 = (long long)n * 16;
    const long long stride = (long long)CVTBLK * 256;
    long long i = (long long)(blockIdx.x - NBLK1) * 256 + threadIdx.x;
    const float4* X4 = (const float4*)X;
    uint2* O = (uint2*)Xh;
    for (; i < total4; i += stride) {
        float4 v = X4[i];
        uint2 o;
        o.x = packh2(v.x, v.y);
        o.y = packh2(v.z, v.w);
        O[i] = o;
    }
}

// ---------- scanA with fused scanB (ticketed last block — single waiter, no spin) ----------
__global__ void scanAB(u32* __restrict__ HG, u32* __restrict__ blockSums,
                       u32* __restrict__ SB, u32* __restrict__ ticket, int n) {
    __shared__ u32 ts[256];
    __shared__ int isLast;
    const int ITEMS = 8;
    const int tid = threadIdx.x;
    int base = blockIdx.x * 2048 + tid * ITEMS;
    u32 v[ITEMS];
    u32 sum = 0;
#pragma unroll
    for (int i = 0; i < ITEMS; ++i) {
        int idx = base + i;
        v[i] = (idx < n) ? HG[idx] : 0;
        sum += v[i];
    }
    ts[tid] = sum;
    __syncthreads();
    u32 incl = sum;
    for (int d = 1; d < 256; d <<= 1) {
        u32 y = 0;
        if (tid >= d) y = ts[tid - d];
        __syncthreads();
        incl += y;
        ts[tid] = incl;
        __syncthreads();
    }
    u32 run = incl - sum;
#pragma unroll
    for (int i = 0; i < ITEMS; ++i) {
        int idx = base + i;
        if (idx < n) HG[idx] = run;
        run += v[i];
    }
    if (tid == 255) {
        atomicExch(&blockSums[blockIdx.x], incl);
        __threadfence();
        u32 t = atomicAdd(&ticket[0], 1u);
        isLast = (t == gridDim.x - 1);
    }
    __syncthreads();
    if (!isLast) return;
    const int nb = gridDim.x;
    u32 bv = (tid < nb) ? atomicAdd(&blockSums[tid], 0u) : 0;
    ts[tid] = bv;
    __syncthreads();
    u32 bincl = bv;
    for (int d = 1; d < 256; d <<= 1) {
        u32 y = 0;
        if (tid >= d) y = ts[tid - d];
        __syncthreads();
        bincl += y;
        ts[tid] = bincl;
        __syncthreads();
    }
    if (tid < nb) SB[tid] = bincl - bv;
}

// ---------- pass 1b: rank via LDS atomics; write packed (dst&511)<<17|src ----------
__global__ void __launch_bounds__(256) p1_scatter(const void* __restrict__ edge,
                                                  const int* __restrict__ flag,
                                                  const u32* __restrict__ HG,
                                                  const u32* __restrict__ SB,
                                                  u32* __restrict__ P, int E, int n, int nb1) {
    __shared__ u32 base[256];
    __shared__ u32 cur[256];
    const int tid = threadIdx.x;
    cur[tid] = 0;
    for (int b = tid; b < nb1; b += 256) {
        int i = b * NBLK1 + blockIdx.x;
        base[b] = HG[i] + SB[i >> 11];
    }
    __syncthreads();
    const int w64 = flag[0];
    const int chunk = (E + NBLK1 - 1) / NBLK1;
    const int s = blockIdx.x * chunk;
    const int e = min(s + chunk, E);
    for (int i = s + tid; i < e; i += 256) {
        int d = gidx(edge, (long long)E + i, w64);
        if ((unsigned)d >= (unsigned)n) d = 0;
        int sv = gidx(edge, i, w64);
        if ((unsigned)sv >= (unsigned)n) sv = 0;
        const int b1 = d >> 9;
        u32 r = atomicAdd(&cur[b1], 1);
        P[base[b1] + r] = (u32)sv | ((u32)(d & 511) << 17);
    }
}

// ---------- pass 2 (512 threads): fine hist, scan, final ss ----------
__global__ void __launch_bounds__(512) p2_kernel(const u32* __restrict__ P,
                                                 const u32* __restrict__ HG,
                                                 const u32* __restrict__ SB,
                                                 u32* __restrict__ offs,
                                                 int* __restrict__ ss,
                                                 float* __restrict__ pool,
                                                 int E, int n, int nb1) {
    __shared__ u32 h2[512];
    __shared__ u32 ts[512];
    const int tid = threadIdx.x;
    const int b = blockIdx.x;
    if (b == 0)
        for (int i = tid; i < 4096; i += 512) pool[i] = 0.f;
    const int i0 = b * NBLK1;
    const int bs = (int)(HG[i0] + SB[i0 >> 11]);
    int be;
    if (b + 1 < nb1) {
        const int i1 = (b + 1) * NBLK1;
        be = (int)(HG[i1] + SB[i1 >> 11]);
    } else be = E;
    h2[tid] = 0;
    __syncthreads();
    for (int i = bs + tid; i < be; i += 512) atomicAdd(&h2[(P[i] >> 17) & 511], 1);
    __syncthreads();
    u32 v = h2[tid];
    ts[tid] = v;
    __syncthreads();
    u32 incl = v;
    for (int d = 1; d < 512; d <<= 1) {
        u32 y = 0;
        if (tid >= d) y = ts[tid - d];
        __syncthreads();
        incl += y;
        ts[tid] = incl;
        __syncthreads();
    }
    u32 run = incl - v;
    h2[tid] = run;
    const int node0 = b * 512 + tid;
    if (node0 < n) offs[node0] = bs + run;
    if (b == 0 && tid == 0) offs[n] = (u32)E;
    __syncthreads();
    for (int i = bs + tid; i < be; i += 512) {
        u32 p = P[i];
        u32 r = atomicAdd(&h2[(p >> 17) & 511], 1);
        ss[bs + r] = (int)(p & 0x1FFFFu);
    }
}

// ---------- fused SAGE layer v2: gather+mean+MFMA, LDS-staged weights ----------
// H = relu( mean_j G[src_j] @ Wl + b + G[i] @ Wr ).  Weights staged once per block
// into LDS in MFMA-fragment layout (ds_read_b128 per (kh,t)); VGPR target <=64 for
// 8 waves/SIMD.  Wave = one 16-node tile; lane (quad,m16) = node m16, k-chunk quad.
// mode 1: fuse global-mean-pool (per-tile cross-quad reduce + 64 atomics/tile).
__global__ void __launch_bounds__(256, 8) sage2(
        const u16* __restrict__ G, const u32* __restrict__ offs,
        const int* __restrict__ ss,
        const float* __restrict__ Wl, const float* __restrict__ Wr,
        const float* __restrict__ Bv,
        u16* __restrict__ Hout, float* __restrict__ pool,
        const void* __restrict__ batch, const int* __restrict__ flag,
        int n, int mode) {
    __shared__ _Float16 WlS[4096];
    __shared__ _Float16 WrS[4096];
    __shared__ float BS[64];
    const int tid = threadIdx.x;
    // stage weights into fragment layout: dst = (((kh*4+q)*4+t)*16 + m)*8 + j
    // where src k = kh*32+q*8+j (K index), c = t*16+m (col index)
    for (int idx = tid; idx < 4096; idx += 256) {
        const int k = idx >> 6, c = idx & 63;
        const int dst = ((((k >> 5) * 4 + ((k >> 3) & 3)) * 4 + (c >> 4)) * 16 + (c & 15)) * 8
                        + (k & 7);
        WlS[dst] = (_Float16)Wl[idx];
        WrS[dst] = (_Float16)Wr[idx];
    }
    if (tid < 64) BS[tid] = Bv[tid];
    __syncthreads();

    const int lane = tid & 63;
    const int quad = lane >> 4;
    const int m16 = lane & 15;
    const int w64 = mode ? flag[0] : 0;
    // per-lane LDS fragment bases (halfword units): frag(kh,t) at base + kh*2048 + t*256
    const _Float16* wlp = WlS + (quad * 4 * 16 + m16) * 8;
    const _Float16* wrp = WrS + (quad * 4 * 16 + m16) * 8;

    const int ntiles = (n + 15) >> 4;
    const int nwaves = gridDim.x * 4;
    for (int tile = blockIdx.x * 4 + (tid >> 6); tile < ntiles; tile += nwaves) {
        const int nodeBase = tile << 4;
        const int node_m = nodeBase + m16;
        const int nodeA = node_m < n ? node_m : n - 1;
        const u32 o0 = offs[nodeA];
        const int deg = node_m < n ? (int)(offs[nodeA + 1] - o0) : 0;
        const int* sp = ss + o0;
        f16x8 s0, s1;
#pragma unroll
        for (int j = 0; j < 8; ++j) { s0[j] = (_Float16)0; s1[j] = (_Float16)0; }
        int e = 0;
        for (; e + 4 <= deg; e += 4) {   // 8x 16B loads in flight per lane
            const int iA = sp[e], iB = sp[e + 1], iC = sp[e + 2], iD = sp[e + 3];
            const f16x8* pA = (const f16x8*)(G + ((size_t)iA << 6)) + quad;
            const f16x8* pB = (const f16x8*)(G + ((size_t)iB << 6)) + quad;
            const f16x8* pC = (const f16x8*)(G + ((size_t)iC << 6)) + quad;
            const f16x8* pD = (const f16x8*)(G + ((size_t)iD << 6)) + quad;
            f16x8 a0 = pA[0], a1 = pA[4];
            f16x8 b0 = pB[0], b1 = pB[4];
            f16x8 c0 = pC[0], c1 = pC[4];
            f16x8 d0 = pD[0], d1 = pD[4];
            s0 += a0; s1 += a1;
            s0 += b0; s1 += b1;
            s0 += c0; s1 += c1;
            s0 += d0; s1 += d1;
        }
        for (; e < deg; ++e) {
            const f16x8* pA = (const f16x8*)(G + ((size_t)(sp[e]) << 6)) + quad;
            s0 += pA[0]; s1 += pA[4];
        }
        // mean: scale the fp16 sum (row scaling commutes with A@Wl)
        const float rdf = deg > 0 ? 1.f / (float)deg : 0.f;
        const _Float16 hrd = (_Float16)rdf;
#pragma unroll
        for (int j = 0; j < 8; ++j) { s0[j] *= hrd; s1[j] *= hrd; }
        // self rows (coalesced: 16 consecutive rows per tile)
        const f16x8 as0 = *(const f16x8*)(G + (size_t)nodeA * 64 + quad * 8);
        const f16x8 as1 = *(const f16x8*)(G + (size_t)nodeA * 64 + 32 + quad * 8);
#pragma unroll
        for (int t = 0; t < 4; ++t) {
            const float bt = BS[t * 16 + m16];
            const f16x8 l0 = *(const f16x8*)(wlp + t * 128);
            const f16x8 l1 = *(const f16x8*)(wlp + 2048 + t * 128);
            const f16x8 r0 = *(const f16x8*)(wrp + t * 128);
            const f16x8 r1 = *(const f16x8*)(wrp + 2048 + t * 128);
            f32x4 acc = {bt, bt, bt, bt};
            acc = __builtin_amdgcn_mfma_f32_16x16x32_f16(s0, l0, acc, 0, 0, 0);
            acc = __builtin_amdgcn_mfma_f32_16x16x32_f16(s1, l1, acc, 0, 0, 0);
            acc = __builtin_amdgcn_mfma_f32_16x16x32_f16(as0, r0, acc, 0, 0, 0);
            acc = __builtin_amdgcn_mfma_f32_16x16x32_f16(as1, r1, acc, 0, 0, 0);
            if (mode == 0) {
#pragma unroll
                for (int rg = 0; rg < 4; ++rg) {
                    const int node = nodeBase + quad * 4 + rg;
                    if (node < n)
                        Hout[(size_t)node * 64 + t * 16 + m16] = f2h(fmaxf(acc[rg], 0.f));
                }
            } else {
                float v0 = fmaxf(acc[0], 0.f), v1 = fmaxf(acc[1], 0.f);
                float v2 = fmaxf(acc[2], 0.f), v3 = fmaxf(acc[3], 0.f);
                const int lastN = nodeBase + 15 < n ? nodeBase + 15 : n - 1;
                const int g0 = gidx(batch, nodeBase, w64) & 63;
                const int g1 = gidx(batch, lastN, w64) & 63;
                if (nodeBase + 15 < n && g0 == g1) {
                    float cs = v0 + v1 + v2 + v3;
                    cs += __shfl_xor(cs, 16, 64);
                    cs += __shfl_xor(cs, 32, 64);
                    if (quad == 0) atomicAdd(&pool[g0 * 64 + t * 16 + m16], cs);
                } else {  // graph-boundary tile (rare): per-node atomics
                    const float vv[4] = {v0, v1, v2, v3};
#pragma unroll
                    for (int rg = 0; rg < 4; ++rg) {
                        const int node = nodeBase + quad * 4 + rg;
                        if (node < n) {
                            const int g = gidx(batch, node, w64) & 63;
                            atomicAdd(&pool[g * 64 + t * 16 + m16], vv[rg]);
                        }
                    }
                }
            }
        }
    }
}

// ---------- head MLP: out = relu(g@Wc1+bc1)@Wc2 + bc2 ----------
__global__ void head_kernel(const float* __restrict__ pool, const void* __restrict__ batch,
                            const int* __restrict__ flag,
                            const float* __restrict__ Wc1, const float* __restrict__ bc1,
                            const float* __restrict__ Wc2, const float* __restrict__ bc2,
                            float* __restrict__ out, int n) {
    __shared__ float gm[64 * 64];
    __shared__ float am[64 * 32];
    __shared__ int cnts[64];
    const int tid = threadIdx.x;  // 256
    const int w64 = flag[0];
    if (tid < 64) {
        int lo = 0, hi = n;
        while (lo < hi) { int mid = (lo + hi) >> 1; if (gidx(batch, mid, w64) < tid) lo = mid + 1; else hi = mid; }
        int lo2 = 0, hi2 = n;
        int v2 = tid + 1;
        while (lo2 < hi2) { int mid = (lo2 + hi2) >> 1; if (gidx(batch, mid, w64) < v2) lo2 = mid + 1; else hi2 = mid; }
        cnts[tid] = lo2 - lo;
    }
    __syncthreads();
    for (int i = tid; i < 4096; i += 256) {
        int g = i >> 6;
        float c = (float)(cnts[g] > 0 ? cnts[g] : 1);
        gm[i] = pool[i] / c;
    }
    __syncthreads();
    for (int i = tid; i < 64 * 32; i += 256) {
        int g = i >> 5, j = i & 31;
        float acc = bc1[j];
        for (int k = 0; k < 64; ++k) acc += gm[g * 64 + k] * Wc1[k * 32 + j];
        am[i] = acc > 0.f ? acc : 0.f;
    }
    __syncthreads();
    if (tid < 128) {
        int g = tid >> 1, o = tid & 1;
        float acc = bc2[o];
        for (int j = 0; j < 32; ++j) acc += am[g * 32 + j] * Wc2[j * 2 + o];
        out[tid] = acc;
    }
}

extern "C" void kernel_launch(void* const* d_in, const int* in_sizes, int n_in,
                              void* d_out, int out_size, void* d_ws, size_t ws_size,
                              hipStream_t stream) {
    const float* x   = (const float*)d_in[0];
    const void* edge = d_in[1];     // int32 or int64, auto-detected
    const void* batch = d_in[2];
    const float* W1l = (const float*)d_in[3];
    const float* b1  = (const float*)d_in[4];
    const float* W1r = (const float*)d_in[5];
    const float* W2l = (const float*)d_in[6];
    const float* b2  = (const float*)d_in[7];
    const float* W2r = (const float*)d_in[8];
    const float* W3l = (const float*)d_in[9];
    const float* b3  = (const float*)d_in[10];
    const float* W3r = (const float*)d_in[11];
    const float* Wc1 = (const float*)d_in[12];
    const float* bc1 = (const float*)d_in[13];
    const float* Wc2 = (const float*)d_in[14];
    const float* bc2 = (const float*)d_in[15];

    const int n = in_sizes[0] / 64;   // 100000
    const int E = in_sizes[1] / 2;    // 1600000
    const int nb1 = (n + 511) >> 9;   // 196 coarse buckets (requires <= 256)
    const int NS = nb1 * NBLK1;       // scanned histogram length

    char* w = (char*)d_ws;
    size_t o = 0;
    auto take = [&](size_t bytes) -> void* {
        void* p = w + o;
        o = (o + bytes + 511) & ~(size_t)511;
        return p;
    };
    int* flag      = (int*)take(sizeof(int));
    u32* ticket    = (u32*)take(2 * sizeof(u32));
    u32* offs      = (u32*)take((size_t)(n + 1) * sizeof(u32));
    u32* HG        = (u32*)take((size_t)(NS + 1) * sizeof(u32));
    u32* blockSums = (u32*)take(256 * sizeof(u32));
    u32* SB        = (u32*)take(256 * sizeof(u32));
    u32* P         = (u32*)take((size_t)E * sizeof(u32));
    int* ss        = (int*)take((size_t)E * sizeof(int));
    u16* Xh        = (u16*)take((size_t)n * 64 * sizeof(u16));
    u16* HA        = (u16*)take((size_t)n * 64 * sizeof(u16));
    u16* HB        = (u16*)take((size_t)n * 64 * sizeof(u16));
    float* pool    = (float*)take(64 * 64 * sizeof(float));

    // CSR coarse hist + X->fp16 convert in one launch (also writes flag/ticket)
    fused_hist_cvt<<<NBLK1 + CVTBLK, 256, 0, stream>>>(edge, flag, ticket, HG, E, n, nb1,
                                                       x, Xh);
    const int nbScan = (NS + 2047) / 2048;
    scanAB<<<nbScan, 256, 0, stream>>>(HG, blockSums, SB, ticket, NS);
    p1_scatter<<<NBLK1, 256, 0, stream>>>(edge, flag, HG, SB, P, E, n, nb1);
    p2_kernel<<<nb1, 512, 0, stream>>>(P, HG, SB, offs, ss, pool, E, n, nb1);

    const int ntiles = (n + 15) >> 4;
    const int SLBLK = (ntiles + 3) >> 2;   // 1 wave per 16-node tile
    sage2<<<SLBLK, 256, 0, stream>>>(Xh, offs, ss, W1l, W1r, b1, HA, nullptr,
                                     batch, flag, n, 0);
    sage2<<<SLBLK, 256, 0, stream>>>(HA, offs, ss, W2l, W2r, b2, HB, nullptr,
                                     batch, flag, n, 0);
    sage2<<<SLBLK, 256, 0, stream>>>(HB, offs, ss, W3l, W3r, b3, nullptr, pool,
                                     batch, flag, n, 1);
    head_kernel<<<1, 256, 0, stream>>>(pool, batch, flag, Wc1, bc1, Wc2, bc2,
                                       (float*)d_out, n);
}

// Round 6
// 306.216 us; speedup vs baseline: 1.3338x; 1.3338x over previous
//
#include <hip/hip_runtime.h>
#include <hip/hip_bf16.h>
#include <hip/hip_fp16.h>

typedef unsigned int u32;
typedef unsigned short u16;
typedef _Float16 f16x8 __attribute__((ext_vector_type(8)));
typedef float f32x4 __attribute__((ext_vector_type(4)));

#define NBLK1 512   // pass-1 blocks (edge chunks)
#define CVTBLK 256  // X->fp16 convert blocks fused into k1
#define MMBLK 784   // mm blocks: ~2 tiles/wave, ~12 waves/CU (fix for 1-wave/SIMD latency)
#define AGGBLK 2048 // agg blocks (half-row waves; proven ~29us in round 4)

// ---------- fp16 pack helpers ----------
__device__ __forceinline__ u16 f2h(float f) { return __half_as_ushort(__float2half(f)); }
__device__ __forceinline__ u32 packh2(float a, float b) {
    return (u32)f2h(a) | ((u32)f2h(b) << 16);
}

// ---------- int-width-agnostic index load (w64=1 -> int64 data on device) ----------
__device__ __forceinline__ int gidx(const void* p, long long i, int w64) {
    if (w64) return (int)((const long long*)p)[i];
    return ((const int*)p)[i];
}

// per-block int64 detection (probe odd words; int32 data -> some nonzero, int64 -> all zero)
__device__ __forceinline__ int detect_w64(const int* edge_words, int E, int tid, int* sh) {
    if (tid == 0) *sh = 0;
    __syncthreads();
    const long long totalWords = 2LL * E;
    const long long step = totalWords / 256;
    long long w = ((long long)tid * step) | 1;
    int nz = (w < totalWords) ? edge_words[w] : 0;
    if (nz) atomicOr(sh, 1);
    __syncthreads();
    return (*sh) ? 0 : 1;
}

// ---------- fused: p1 coarse hist (blocks < NBLK1) + X -> fp16 convert (rest) ----------
__global__ void __launch_bounds__(256) fused_hist_cvt(
        const void* __restrict__ edge, int* __restrict__ flag, u32* __restrict__ ticket,
        u32* __restrict__ HG, int E, int n, int nb1,
        const float* __restrict__ X, u16* __restrict__ Xh) {
    if (blockIdx.x < NBLK1) {
        __shared__ u32 h[256];
        __shared__ int shnz;
        const int tid = threadIdx.x;
        h[tid] = 0;
        const int w64 = detect_w64((const int*)edge, E, tid, &shnz);
        if (blockIdx.x == 0 && tid == 0) { flag[0] = w64; ticket[0] = 0; }
        __syncthreads();
        const int chunk = (E + NBLK1 - 1) / NBLK1;
        const int s = blockIdx.x * chunk;
        const int e = min(s + chunk, E);
        for (int i = s + tid; i < e; i += 256) {
            int d = gidx(edge, (long long)E + i, w64);
            if ((unsigned)d >= (unsigned)n) d = 0;
            atomicAdd(&h[d >> 9], 1);
        }
        __syncthreads();
        for (int b = tid; b < nb1; b += 256) HG[b * NBLK1 + blockIdx.x] = h[b];
        return;
    }
    // elementwise convert X (fp32) -> Xh (fp16), 4 elems / thread / iter
    const long long total4 = (long long)n * 16;
    const long long stride = (long long)CVTBLK * 256;
    long long i = (long long)(blockIdx.x - NBLK1) * 256 + threadIdx.x;
    const float4* X4 = (const float4*)X;
    uint2* O = (uint2*)Xh;
    for (; i < total4; i += stride) {
        float4 v = X4[i];
        uint2 o;
        o.x = packh2(v.x, v.y);
        o.y = packh2(v.z, v.w);
        O[i] = o;
    }
}

// ---------- scanA with fused scanB (ticketed last block — single waiter, no spin) ----------
__global__ void scanAB(u32* __restrict__ HG, u32* __restrict__ blockSums,
                       u32* __restrict__ SB, u32* __restrict__ ticket, int n) {
    __shared__ u32 ts[256];
    __shared__ int isLast;
    const int ITEMS = 8;
    const int tid = threadIdx.x;
    int base = blockIdx.x * 2048 + tid * ITEMS;
    u32 v[ITEMS];
    u32 sum = 0;
#pragma unroll
    for (int i = 0; i < ITEMS; ++i) {
        int idx = base + i;
        v[i] = (idx < n) ? HG[idx] : 0;
        sum += v[i];
    }
    ts[tid] = sum;
    __syncthreads();
    u32 incl = sum;
    for (int d = 1; d < 256; d <<= 1) {
        u32 y = 0;
        if (tid >= d) y = ts[tid - d];
        __syncthreads();
        incl += y;
        ts[tid] = incl;
        __syncthreads();
    }
    u32 run = incl - sum;
#pragma unroll
    for (int i = 0; i < ITEMS; ++i) {
        int idx = base + i;
        if (idx < n) HG[idx] = run;
        run += v[i];
    }
    if (tid == 255) {
        atomicExch(&blockSums[blockIdx.x], incl);
        __threadfence();
        u32 t = atomicAdd(&ticket[0], 1u);
        isLast = (t == gridDim.x - 1);
    }
    __syncthreads();
    if (!isLast) return;
    const int nb = gridDim.x;
    u32 bv = (tid < nb) ? atomicAdd(&blockSums[tid], 0u) : 0;
    ts[tid] = bv;
    __syncthreads();
    u32 bincl = bv;
    for (int d = 1; d < 256; d <<= 1) {
        u32 y = 0;
        if (tid >= d) y = ts[tid - d];
        __syncthreads();
        bincl += y;
        ts[tid] = bincl;
        __syncthreads();
    }
    if (tid < nb) SB[tid] = bincl - bv;
}

// ---------- pass 1b: rank via LDS atomics; write packed (dst&511)<<17|src ----------
__global__ void __launch_bounds__(256) p1_scatter(const void* __restrict__ edge,
                                                  const int* __restrict__ flag,
                                                  const u32* __restrict__ HG,
                                                  const u32* __restrict__ SB,
                                                  u32* __restrict__ P, int E, int n, int nb1) {
    __shared__ u32 base[256];
    __shared__ u32 cur[256];
    const int tid = threadIdx.x;
    cur[tid] = 0;
    for (int b = tid; b < nb1; b += 256) {
        int i = b * NBLK1 + blockIdx.x;
        base[b] = HG[i] + SB[i >> 11];
    }
    __syncthreads();
    const int w64 = flag[0];
    const int chunk = (E + NBLK1 - 1) / NBLK1;
    const int s = blockIdx.x * chunk;
    const int e = min(s + chunk, E);
    for (int i = s + tid; i < e; i += 256) {
        int d = gidx(edge, (long long)E + i, w64);
        if ((unsigned)d >= (unsigned)n) d = 0;
        int sv = gidx(edge, i, w64);
        if ((unsigned)sv >= (unsigned)n) sv = 0;
        const int b1 = d >> 9;
        u32 r = atomicAdd(&cur[b1], 1);
        P[base[b1] + r] = (u32)sv | ((u32)(d & 511) << 17);
    }
}

// ---------- pass 2 (512 threads): fine hist, scan, final ss ----------
__global__ void __launch_bounds__(512) p2_kernel(const u32* __restrict__ P,
                                                 const u32* __restrict__ HG,
                                                 const u32* __restrict__ SB,
                                                 u32* __restrict__ offs,
                                                 int* __restrict__ ss,
                                                 float* __restrict__ pool,
                                                 int E, int n, int nb1) {
    __shared__ u32 h2[512];
    __shared__ u32 ts[512];
    const int tid = threadIdx.x;
    const int b = blockIdx.x;
    if (b == 0)
        for (int i = tid; i < 4096; i += 512) pool[i] = 0.f;
    const int i0 = b * NBLK1;
    const int bs = (int)(HG[i0] + SB[i0 >> 11]);
    int be;
    if (b + 1 < nb1) {
        const int i1 = (b + 1) * NBLK1;
        be = (int)(HG[i1] + SB[i1 >> 11]);
    } else be = E;
    h2[tid] = 0;
    __syncthreads();
    for (int i = bs + tid; i < be; i += 512) atomicAdd(&h2[(P[i] >> 17) & 511], 1);
    __syncthreads();
    u32 v = h2[tid];
    ts[tid] = v;
    __syncthreads();
    u32 incl = v;
    for (int d = 1; d < 512; d <<= 1) {
        u32 y = 0;
        if (tid >= d) y = ts[tid - d];
        __syncthreads();
        incl += y;
        ts[tid] = incl;
        __syncthreads();
    }
    u32 run = incl - v;
    h2[tid] = run;
    const int node0 = b * 512 + tid;
    if (node0 < n) offs[node0] = bs + run;
    if (b == 0 && tid == 0) offs[n] = (u32)E;
    __syncthreads();
    for (int i = bs + tid; i < be; i += 512) {
        u32 p = P[i];
        u32 r = atomicAdd(&h2[(p >> 17) & 511], 1);
        ss[bs + r] = (int)(p & 0x1FFFFu);
    }
}

// ---------- gather+mean, half-row waves (round-4 proven ~29us, VGPR ~20) ----------
// Each wave aggregates 32 channels (one 64B line per edge) for 16 nodes.
// lane (quad,m16): node m16, halfwords [half*32 + quad*8, +8).
__global__ void __launch_bounds__(256, 8) agg_kernel(
        const u16* __restrict__ G, const u32* __restrict__ offs,
        const int* __restrict__ ss, u16* __restrict__ M, int n) {
    const int lane = threadIdx.x & 63;
    const int quad = lane >> 4;
    const int m16 = lane & 15;
    const int gw = blockIdx.x * 4 + (threadIdx.x >> 6);
    const int half = gw & 1;
    const int cb = half * 32 + quad * 8;       // halfword offset within 64-hw row
    const int ntiles = (n + 15) >> 4;
    const int stride = (gridDim.x * 4) >> 1;
    for (int tile = gw >> 1; tile < ntiles; tile += stride) {
        const int node_m = (tile << 4) + m16;
        const int valid = node_m < n;
        const int nodeA = valid ? node_m : n - 1;
        const u32 o0 = offs[nodeA];
        const int deg = valid ? (int)(offs[nodeA + 1] - o0) : 0;
        const int* sp = ss + o0;
        f16x8 s;
#pragma unroll
        for (int j = 0; j < 8; ++j) s[j] = (_Float16)0;
        int e = 0;
        for (; e + 4 <= deg; e += 4) {   // 4 row-chunk loads in flight
            const int iA = sp[e], iB = sp[e + 1], iC = sp[e + 2], iD = sp[e + 3];
            f16x8 a = *(const f16x8*)(G + ((size_t)iA << 6) + cb);
            f16x8 b = *(const f16x8*)(G + ((size_t)iB << 6) + cb);
            f16x8 c = *(const f16x8*)(G + ((size_t)iC << 6) + cb);
            f16x8 d = *(const f16x8*)(G + ((size_t)iD << 6) + cb);
            s += a; s += b; s += c; s += d;
        }
        for (; e < deg; ++e)
            s += *(const f16x8*)(G + ((size_t)(sp[e]) << 6) + cb);
        const float rdf = deg > 0 ? 1.f / (float)deg : 0.f;
        const _Float16 hrd = (_Float16)rdf;
#pragma unroll
        for (int j = 0; j < 8; ++j) s[j] *= hrd;
        if (valid) *(f16x8*)(M + ((size_t)node_m << 6) + cb) = s;
    }
}

// ---------- MFMA transform: H = relu(M@Wl + G@Wr + b), LDS-staged weights ----------
// Plain launch_bounds(256): no min-waves cap -> no spill (round-5 lesson).
// mode 1: fuse global-mean-pool (per-tile cross-quad reduce + 64 atomics/tile).
__global__ void __launch_bounds__(256) mm_fused(
        const u16* __restrict__ M, const u16* __restrict__ G,
        const float* __restrict__ Wl, const float* __restrict__ Wr,
        const float* __restrict__ Bv,
        u16* __restrict__ Hout, float* __restrict__ pool,
        const void* __restrict__ batch, const int* __restrict__ flag,
        int n, int mode) {
    __shared__ _Float16 WlS[4096];
    __shared__ _Float16 WrS[4096];
    __shared__ float BS[64];
    const int tid = threadIdx.x;
    // stage weights into fragment layout: frag(kh,q,t,m,j) at ((kh*4+q)*4+t)*128 + m*8 + j
    // src k = kh*32+q*8+j, c = t*16+m
    for (int idx = tid; idx < 4096; idx += 256) {
        const int k = idx >> 6, c = idx & 63;
        const int dst = ((((k >> 5) * 4 + ((k >> 3) & 3)) * 4 + (c >> 4)) * 16 + (c & 15)) * 8
                        + (k & 7);
        WlS[dst] = (_Float16)Wl[idx];
        WrS[dst] = (_Float16)Wr[idx];
    }
    if (tid < 64) BS[tid] = Bv[tid];
    __syncthreads();

    const int lane = tid & 63;
    const int quad = lane >> 4;
    const int m16 = lane & 15;
    const int w64 = mode ? flag[0] : 0;
    // per-lane LDS fragment bases (halfword units): frag(kh,t) = base + kh*2048 + t*128
    const _Float16* wlp = WlS + (quad * 512 + m16 * 8);
    const _Float16* wrp = WrS + (quad * 512 + m16 * 8);

    const int ntiles = (n + 15) >> 4;
    const int nwaves = gridDim.x * 4;
    for (int tile = blockIdx.x * 4 + (tid >> 6); tile < ntiles; tile += nwaves) {
        const int nodeBase = tile << 4;
        const int node_m = nodeBase + m16;
        const int nodeA = node_m < n ? node_m : n - 1;
        const f16x8 am0 = *(const f16x8*)(M + (size_t)nodeA * 64 + quad * 8);
        const f16x8 am1 = *(const f16x8*)(M + (size_t)nodeA * 64 + 32 + quad * 8);
        const f16x8 as0 = *(const f16x8*)(G + (size_t)nodeA * 64 + quad * 8);
        const f16x8 as1 = *(const f16x8*)(G + (size_t)nodeA * 64 + 32 + quad * 8);
#pragma unroll
        for (int t = 0; t < 4; ++t) {
            const float bt = BS[t * 16 + m16];
            const f16x8 l0 = *(const f16x8*)(wlp + t * 128);
            const f16x8 l1 = *(const f16x8*)(wlp + 2048 + t * 128);
            const f16x8 r0 = *(const f16x8*)(wrp + t * 128);
            const f16x8 r1 = *(const f16x8*)(wrp + 2048 + t * 128);
            f32x4 acc = {bt, bt, bt, bt};
            acc = __builtin_amdgcn_mfma_f32_16x16x32_f16(am0, l0, acc, 0, 0, 0);
            acc = __builtin_amdgcn_mfma_f32_16x16x32_f16(am1, l1, acc, 0, 0, 0);
            acc = __builtin_amdgcn_mfma_f32_16x16x32_f16(as0, r0, acc, 0, 0, 0);
            acc = __builtin_amdgcn_mfma_f32_16x16x32_f16(as1, r1, acc, 0, 0, 0);
            if (mode == 0) {
#pragma unroll
                for (int rg = 0; rg < 4; ++rg) {
                    const int node = nodeBase + quad * 4 + rg;
                    if (node < n)
                        Hout[(size_t)node * 64 + t * 16 + m16] = f2h(fmaxf(acc[rg], 0.f));
                }
            } else {
                float v0 = fmaxf(acc[0], 0.f), v1 = fmaxf(acc[1], 0.f);
                float v2 = fmaxf(acc[2], 0.f), v3 = fmaxf(acc[3], 0.f);
                const int lastN = nodeBase + 15 < n ? nodeBase + 15 : n - 1;
                const int g0 = gidx(batch, nodeBase, w64) & 63;
                const int g1 = gidx(batch, lastN, w64) & 63;
                if (nodeBase + 15 < n && g0 == g1) {
                    float cs = v0 + v1 + v2 + v3;
                    cs += __shfl_xor(cs, 16, 64);
                    cs += __shfl_xor(cs, 32, 64);
                    if (quad == 0) atomicAdd(&pool[g0 * 64 + t * 16 + m16], cs);
                } else {  // graph-boundary tile (rare): per-node atomics
                    const float vv[4] = {v0, v1, v2, v3};
#pragma unroll
                    for (int rg = 0; rg < 4; ++rg) {
                        const int node = nodeBase + quad * 4 + rg;
                        if (node < n) {
                            const int g = gidx(batch, node, w64) & 63;
                            atomicAdd(&pool[g * 64 + t * 16 + m16], vv[rg]);
                        }
                    }
                }
            }
        }
    }
}

// ---------- head MLP: out = relu(g@Wc1+bc1)@Wc2 + bc2 ----------
__global__ void head_kernel(const float* __restrict__ pool, const void* __restrict__ batch,
                            const int* __restrict__ flag,
                            const float* __restrict__ Wc1, const float* __restrict__ bc1,
                            const float* __restrict__ Wc2, const float* __restrict__ bc2,
                            float* __restrict__ out, int n) {
    __shared__ float gm[64 * 64];
    __shared__ float am[64 * 32];
    __shared__ int cnts[64];
    const int tid = threadIdx.x;  // 256
    const int w64 = flag[0];
    if (tid < 64) {
        int lo = 0, hi = n;
        while (lo < hi) { int mid = (lo + hi) >> 1; if (gidx(batch, mid, w64) < tid) lo = mid + 1; else hi = mid; }
        int lo2 = 0, hi2 = n;
        int v2 = tid + 1;
        while (lo2 < hi2) { int mid = (lo2 + hi2) >> 1; if (gidx(batch, mid, w64) < v2) lo2 = mid + 1; else hi2 = mid; }
        cnts[tid] = lo2 - lo;
    }
    __syncthreads();
    for (int i = tid; i < 4096; i += 256) {
        int g = i >> 6;
        float c = (float)(cnts[g] > 0 ? cnts[g] : 1);
        gm[i] = pool[i] / c;
    }
    __syncthreads();
    for (int i = tid; i < 64 * 32; i += 256) {
        int g = i >> 5, j = i & 31;
        float acc = bc1[j];
        for (int k = 0; k < 64; ++k) acc += gm[g * 64 + k] * Wc1[k * 32 + j];
        am[i] = acc > 0.f ? acc : 0.f;
    }
    __syncthreads();
    if (tid < 128) {
        int g = tid >> 1, o = tid & 1;
        float acc = bc2[o];
        for (int j = 0; j < 32; ++j) acc += am[g * 32 + j] * Wc2[j * 2 + o];
        out[tid] = acc;
    }
}

extern "C" void kernel_launch(void* const* d_in, const int* in_sizes, int n_in,
                              void* d_out, int out_size, void* d_ws, size_t ws_size,
                              hipStream_t stream) {
    const float* x   = (const float*)d_in[0];
    const void* edge = d_in[1];     // int32 or int64, auto-detected
    const void* batch = d_in[2];
    const float* W1l = (const float*)d_in[3];
    const float* b1  = (const float*)d_in[4];
    const float* W1r = (const float*)d_in[5];
    const float* W2l = (const float*)d_in[6];
    const float* b2  = (const float*)d_in[7];
    const float* W2r = (const float*)d_in[8];
    const float* W3l = (const float*)d_in[9];
    const float* b3  = (const float*)d_in[10];
    const float* W3r = (const float*)d_in[11];
    const float* Wc1 = (const float*)d_in[12];
    const float* bc1 = (const float*)d_in[13];
    const float* Wc2 = (const float*)d_in[14];
    const float* bc2 = (const float*)d_in[15];

    const int n = in_sizes[0] / 64;   // 100000
    const int E = in_sizes[1] / 2;    // 1600000
    const int nb1 = (n + 511) >> 9;   // 196 coarse buckets (requires <= 256)
    const int NS = nb1 * NBLK1;       // scanned histogram length

    char* w = (char*)d_ws;
    size_t o = 0;
    auto take = [&](size_t bytes) -> void* {
        void* p = w + o;
        o = (o + bytes + 511) & ~(size_t)511;
        return p;
    };
    int* flag      = (int*)take(sizeof(int));
    u32* ticket    = (u32*)take(2 * sizeof(u32));
    u32* offs      = (u32*)take((size_t)(n + 1) * sizeof(u32));
    u32* HG        = (u32*)take((size_t)(NS + 1) * sizeof(u32));
    u32* blockSums = (u32*)take(256 * sizeof(u32));
    u32* SB        = (u32*)take(256 * sizeof(u32));
    u32* P         = (u32*)take((size_t)E * sizeof(u32));
    int* ss        = (int*)take((size_t)E * sizeof(int));
    u16* Xh        = (u16*)take((size_t)n * 64 * sizeof(u16));
    u16* HA        = (u16*)take((size_t)n * 64 * sizeof(u16));
    u16* HB        = (u16*)take((size_t)n * 64 * sizeof(u16));
    u16* M         = (u16*)take((size_t)n * 64 * sizeof(u16));
    float* pool    = (float*)take(64 * 64 * sizeof(float));

    // CSR coarse hist + X->fp16 convert in one launch (also writes flag/ticket)
    fused_hist_cvt<<<NBLK1 + CVTBLK, 256, 0, stream>>>(edge, flag, ticket, HG, E, n, nb1,
                                                       x, Xh);
    const int nbScan = (NS + 2047) / 2048;
    scanAB<<<nbScan, 256, 0, stream>>>(HG, blockSums, SB, ticket, NS);
    p1_scatter<<<NBLK1, 256, 0, stream>>>(edge, flag, HG, SB, P, E, n, nb1);
    p2_kernel<<<nb1, 512, 0, stream>>>(P, HG, SB, offs, ss, pool, E, n, nb1);

    agg_kernel<<<AGGBLK, 256, 0, stream>>>(Xh, offs, ss, M, n);
    mm_fused<<<MMBLK, 256, 0, stream>>>(M, Xh, W1l, W1r, b1, HA, nullptr, batch, flag, n, 0);
    agg_kernel<<<AGGBLK, 256, 0, stream>>>(HA, offs, ss, M, n);
    mm_fused<<<MMBLK, 256, 0, stream>>>(M, HA, W2l, W2r, b2, HB, nullptr, batch, flag, n, 0);
    agg_kernel<<<AGGBLK, 256, 0, stream>>>(HB, offs, ss, M, n);
    mm_fused<<<MMBLK, 256, 0, stream>>>(M, HB, W3l, W3r, b3, nullptr, pool, batch, flag, n, 1);

    head_kernel<<<1, 256, 0, stream>>>(pool, batch, flag, Wc1, bc1, Wc2, bc2,
                                       (float*)d_out, n);
}

// Round 7
// 294.816 us; speedup vs baseline: 1.3853x; 1.0387x over previous
//
#include <hip/hip_runtime.h>
#include <hip/hip_bf16.h>
#include <hip/hip_fp16.h>

typedef unsigned int u32;
typedef unsigned short u16;
typedef _Float16 f16x8 __attribute__((ext_vector_type(8)));
typedef float f32x4 __attribute__((ext_vector_type(4)));

#define NBLK1 512   // pass-1 blocks (edge chunks)
#define CVTBLK 256  // X->fp16 convert blocks fused into k1
#define WPREP 6     // weight-fragment prep blocks fused into k1

// ---------- fp16 pack helpers ----------
__device__ __forceinline__ u16 f2h(float f) { return __half_as_ushort(__float2half(f)); }
__device__ __forceinline__ u32 packh2(float a, float b) {
    return (u32)f2h(a) | ((u32)f2h(b) << 16);
}

// ---------- int-width-agnostic index load (w64=1 -> int64 data on device) ----------
__device__ __forceinline__ int gidx(const void* p, long long i, int w64) {
    if (w64) return (int)((const long long*)p)[i];
    return ((const int*)p)[i];
}

// per-block int64 detection (probe odd words; int32 data -> some nonzero, int64 -> all zero)
__device__ __forceinline__ int detect_w64(const int* edge_words, int E, int tid, int* sh) {
    if (tid == 0) *sh = 0;
    __syncthreads();
    const long long totalWords = 2LL * E;
    const long long step = totalWords / 256;
    long long w = ((long long)tid * step) | 1;
    int nz = (w < totalWords) ? edge_words[w] : 0;
    if (nz) atomicOr(sh, 1);
    __syncthreads();
    return (*sh) ? 0 : 1;
}

// ---------- fused k1: coarse hist | X->fp16 convert | weight-fragment prep ----------
// Fragment layout (halfword idx): frag(kh,q,t,m,j) at ((kh*4+q)*4+t)*128 + m*8 + j
// where source element k = kh*32+q*8+j (K index), c = t*16+m (col). Lane (q,m)
// then reads frag(kh,t) as one coalesced 16B chunk at byte ((kh*4+q)*4+t)*256 + m*16.
__global__ void __launch_bounds__(256) fused_hist_cvt(
        const void* __restrict__ edge, int* __restrict__ flag, u32* __restrict__ ticket,
        u32* __restrict__ HG, int E, int n, int nb1,
        const float* __restrict__ X, u16* __restrict__ Xh,
        const float* __restrict__ W1l, const float* __restrict__ W1r,
        const float* __restrict__ W2l, const float* __restrict__ W2r,
        const float* __restrict__ W3l, const float* __restrict__ W3r,
        _Float16* __restrict__ WFrag) {
    const int tid = threadIdx.x;
    if (blockIdx.x < NBLK1) {
        __shared__ u32 h[256];
        __shared__ int shnz;
        h[tid] = 0;
        const int w64 = detect_w64((const int*)edge, E, tid, &shnz);
        if (blockIdx.x == 0 && tid == 0) { flag[0] = w64; ticket[0] = 0; }
        __syncthreads();
        const int chunk = (E + NBLK1 - 1) / NBLK1;
        const int s = blockIdx.x * chunk;
        const int e = min(s + chunk, E);
        for (int i = s + tid; i < e; i += 256) {
            int d = gidx(edge, (long long)E + i, w64);
            if ((unsigned)d >= (unsigned)n) d = 0;
            atomicAdd(&h[d >> 9], 1);
        }
        __syncthreads();
        for (int b = tid; b < nb1; b += 256) HG[b * NBLK1 + blockIdx.x] = h[b];
        return;
    }
    if (blockIdx.x >= NBLK1 + CVTBLK) {
        // weight-fragment prep: block b handles one of 6 matrices
        const int b = blockIdx.x - NBLK1 - CVTBLK;   // 0..5
        const float* Ws[WPREP] = {W1l, W1r, W2l, W2r, W3l, W3r};
        const float* src = Ws[b];
        _Float16* dst = WFrag + b * 4096;
        for (int idx = tid; idx < 4096; idx += 256) {
            const int k = idx >> 6, c = idx & 63;
            const int d = ((((k >> 5) * 4 + ((k >> 3) & 3)) * 4 + (c >> 4)) * 16 + (c & 15)) * 8
                          + (k & 7);
            dst[d] = (_Float16)src[idx];
        }
        return;
    }
    // elementwise convert X (fp32) -> Xh (fp16), 4 elems / thread / iter
    const long long total4 = (long long)n * 16;
    const long long stride = (long long)CVTBLK * 256;
    long long i = (long long)(blockIdx.x - NBLK1) * 256 + tid;
    const float4* X4 = (const float4*)X;
    uint2* O = (uint2*)Xh;
    for (; i < total4; i += stride) {
        float4 v = X4[i];
        uint2 o;
        o.x = packh2(v.x, v.y);
        o.y = packh2(v.z, v.w);
        O[i] = o;
    }
}

// ---------- scanA with fused scanB (ticketed last block — single waiter, no spin) ----------
__global__ void scanAB(u32* __restrict__ HG, u32* __restrict__ blockSums,
                       u32* __restrict__ SB, u32* __restrict__ ticket, int n) {
    __shared__ u32 ts[256];
    __shared__ int isLast;
    const int ITEMS = 8;
    const int tid = threadIdx.x;
    int base = blockIdx.x * 2048 + tid * ITEMS;
    u32 v[ITEMS];
    u32 sum = 0;
#pragma unroll
    for (int i = 0; i < ITEMS; ++i) {
        int idx = base + i;
        v[i] = (idx < n) ? HG[idx] : 0;
        sum += v[i];
    }
    ts[tid] = sum;
    __syncthreads();
    u32 incl = sum;
    for (int d = 1; d < 256; d <<= 1) {
        u32 y = 0;
        if (tid >= d) y = ts[tid - d];
        __syncthreads();
        incl += y;
        ts[tid] = incl;
        __syncthreads();
    }
    u32 run = incl - sum;
#pragma unroll
    for (int i = 0; i < ITEMS; ++i) {
        int idx = base + i;
        if (idx < n) HG[idx] = run;
        run += v[i];
    }
    if (tid == 255) {
        atomicExch(&blockSums[blockIdx.x], incl);
        __threadfence();
        u32 t = atomicAdd(&ticket[0], 1u);
        isLast = (t == gridDim.x - 1);
    }
    __syncthreads();
    if (!isLast) return;
    const int nb = gridDim.x;
    u32 bv = (tid < nb) ? atomicAdd(&blockSums[tid], 0u) : 0;
    ts[tid] = bv;
    __syncthreads();
    u32 bincl = bv;
    for (int d = 1; d < 256; d <<= 1) {
        u32 y = 0;
        if (tid >= d) y = ts[tid - d];
        __syncthreads();
        bincl += y;
        ts[tid] = bincl;
        __syncthreads();
    }
    if (tid < nb) SB[tid] = bincl - bv;
}

// ---------- pass 1b: rank via LDS atomics; write packed (dst&511)<<17|src ----------
__global__ void __launch_bounds__(256) p1_scatter(const void* __restrict__ edge,
                                                  const int* __restrict__ flag,
                                                  const u32* __restrict__ HG,
                                                  const u32* __restrict__ SB,
                                                  u32* __restrict__ P, int E, int n, int nb1) {
    __shared__ u32 base[256];
    __shared__ u32 cur[256];
    const int tid = threadIdx.x;
    cur[tid] = 0;
    for (int b = tid; b < nb1; b += 256) {
        int i = b * NBLK1 + blockIdx.x;
        base[b] = HG[i] + SB[i >> 11];
    }
    __syncthreads();
    const int w64 = flag[0];
    const int chunk = (E + NBLK1 - 1) / NBLK1;
    const int s = blockIdx.x * chunk;
    const int e = min(s + chunk, E);
    for (int i = s + tid; i < e; i += 256) {
        int d = gidx(edge, (long long)E + i, w64);
        if ((unsigned)d >= (unsigned)n) d = 0;
        int sv = gidx(edge, i, w64);
        if ((unsigned)sv >= (unsigned)n) sv = 0;
        const int b1 = d >> 9;
        u32 r = atomicAdd(&cur[b1], 1);
        P[base[b1] + r] = (u32)sv | ((u32)(d & 511) << 17);
    }
}

// ---------- pass 2 (512 threads): fine hist, scan, final ss ----------
__global__ void __launch_bounds__(512) p2_kernel(const u32* __restrict__ P,
                                                 const u32* __restrict__ HG,
                                                 const u32* __restrict__ SB,
                                                 u32* __restrict__ offs,
                                                 int* __restrict__ ss,
                                                 float* __restrict__ pool,
                                                 int E, int n, int nb1) {
    __shared__ u32 h2[512];
    __shared__ u32 ts[512];
    const int tid = threadIdx.x;
    const int b = blockIdx.x;
    if (b == 0)
        for (int i = tid; i < 4096; i += 512) pool[i] = 0.f;
    const int i0 = b * NBLK1;
    const int bs = (int)(HG[i0] + SB[i0 >> 11]);
    int be;
    if (b + 1 < nb1) {
        const int i1 = (b + 1) * NBLK1;
        be = (int)(HG[i1] + SB[i1 >> 11]);
    } else be = E;
    h2[tid] = 0;
    __syncthreads();
    for (int i = bs + tid; i < be; i += 512) atomicAdd(&h2[(P[i] >> 17) & 511], 1);
    __syncthreads();
    u32 v = h2[tid];
    ts[tid] = v;
    __syncthreads();
    u32 incl = v;
    for (int d = 1; d < 512; d <<= 1) {
        u32 y = 0;
        if (tid >= d) y = ts[tid - d];
        __syncthreads();
        incl += y;
        ts[tid] = incl;
        __syncthreads();
    }
    u32 run = incl - v;
    h2[tid] = run;
    const int node0 = b * 512 + tid;
    if (node0 < n) offs[node0] = bs + run;
    if (b == 0 && tid == 0) offs[n] = (u32)E;
    __syncthreads();
    for (int i = bs + tid; i < be; i += 512) {
        u32 p = P[i];
        u32 r = atomicAdd(&h2[(p >> 17) & 511], 1);
        ss[bs + r] = (int)(p & 0x1FFFFu);
    }
}

// ---------- fused SAGE layer v3: gather+mean+MFMA, global frag weights ----------
// H = relu( mean_j G[src_j] @ Wl + b + G[i] @ Wr ).  Weight fragments come from the
// precomputed L2-hot WF table (16KB/layer-side) via coalesced 16B loads per tile —
// no LDS, no barrier, no per-block staging.  Plain launch_bounds(256): no min-wave
// cap -> no scratch spill (round-5 lesson).  Wave = one 16-node tile.
// mode 1: fuse global-mean-pool (per-tile cross-quad reduce + 64 atomics/tile).
__global__ void __launch_bounds__(256) sage3(
        const u16* __restrict__ G, const u32* __restrict__ offs,
        const int* __restrict__ ss,
        const _Float16* __restrict__ WF,   // [2][4096]: Wl frags | Wr frags
        const float* __restrict__ Bv,
        u16* __restrict__ Hout, float* __restrict__ pool,
        const void* __restrict__ batch, const int* __restrict__ flag,
        int n, int mode) {
    const int tid = threadIdx.x;
    const int lane = tid & 63;
    const int quad = lane >> 4;
    const int m16 = lane & 15;
    const int w64 = mode ? flag[0] : 0;
    // per-lane frag base (halfwords): frag(kh,t) = base + kh*2048 + t*128
    const _Float16* wlp = WF + quad * 512 + m16 * 8;
    const _Float16* wrp = wlp + 4096;
    const float btv[4] = {Bv[m16], Bv[16 + m16], Bv[32 + m16], Bv[48 + m16]};

    const int ntiles = (n + 15) >> 4;
    const int nwaves = gridDim.x * 4;
    for (int tile = blockIdx.x * 4 + (tid >> 6); tile < ntiles; tile += nwaves) {
        const int nodeBase = tile << 4;
        const int node_m = nodeBase + m16;
        const int nodeA = node_m < n ? node_m : n - 1;
        const u32 o0 = offs[nodeA];
        const int deg = node_m < n ? (int)(offs[nodeA + 1] - o0) : 0;
        const int* sp = ss + o0;
        f16x8 s0, s1;
#pragma unroll
        for (int j = 0; j < 8; ++j) { s0[j] = (_Float16)0; s1[j] = (_Float16)0; }
        int e = 0;
        for (; e + 4 <= deg; e += 4) {   // 8x 16B loads in flight per lane
            const int iA = sp[e], iB = sp[e + 1], iC = sp[e + 2], iD = sp[e + 3];
            const f16x8* pA = (const f16x8*)(G + ((size_t)iA << 6)) + quad;
            const f16x8* pB = (const f16x8*)(G + ((size_t)iB << 6)) + quad;
            const f16x8* pC = (const f16x8*)(G + ((size_t)iC << 6)) + quad;
            const f16x8* pD = (const f16x8*)(G + ((size_t)iD << 6)) + quad;
            f16x8 a0 = pA[0], a1 = pA[4];
            f16x8 b0 = pB[0], b1 = pB[4];
            f16x8 c0 = pC[0], c1 = pC[4];
            f16x8 d0 = pD[0], d1 = pD[4];
            s0 += a0; s1 += a1;
            s0 += b0; s1 += b1;
            s0 += c0; s1 += c1;
            s0 += d0; s1 += d1;
        }
        for (; e < deg; ++e) {
            const f16x8* pA = (const f16x8*)(G + ((size_t)(sp[e]) << 6)) + quad;
            s0 += pA[0]; s1 += pA[4];
        }
        // mean: scale the fp16 sum (row scaling commutes with A@Wl)
        const float rdf = deg > 0 ? 1.f / (float)deg : 0.f;
        const _Float16 hrd = (_Float16)rdf;
#pragma unroll
        for (int j = 0; j < 8; ++j) { s0[j] *= hrd; s1[j] *= hrd; }
        // self rows (coalesced: 16 consecutive rows per tile)
        const f16x8 as0 = *(const f16x8*)(G + (size_t)nodeA * 64 + quad * 8);
        const f16x8 as1 = *(const f16x8*)(G + (size_t)nodeA * 64 + 32 + quad * 8);
#pragma unroll
        for (int t = 0; t < 4; ++t) {
            const f16x8 l0 = *(const f16x8*)(wlp + t * 128);
            const f16x8 l1 = *(const f16x8*)(wlp + 2048 + t * 128);
            const f16x8 r0 = *(const f16x8*)(wrp + t * 128);
            const f16x8 r1 = *(const f16x8*)(wrp + 2048 + t * 128);
            const float bt = btv[t];
            f32x4 acc = {bt, bt, bt, bt};
            acc = __builtin_amdgcn_mfma_f32_16x16x32_f16(s0, l0, acc, 0, 0, 0);
            acc = __builtin_amdgcn_mfma_f32_16x16x32_f16(s1, l1, acc, 0, 0, 0);
            acc = __builtin_amdgcn_mfma_f32_16x16x32_f16(as0, r0, acc, 0, 0, 0);
            acc = __builtin_amdgcn_mfma_f32_16x16x32_f16(as1, r1, acc, 0, 0, 0);
            if (mode == 0) {
#pragma unroll
                for (int rg = 0; rg < 4; ++rg) {
                    const int node = nodeBase + quad * 4 + rg;
                    if (node < n)
                        Hout[(size_t)node * 64 + t * 16 + m16] = f2h(fmaxf(acc[rg], 0.f));
                }
            } else {
                float v0 = fmaxf(acc[0], 0.f), v1 = fmaxf(acc[1], 0.f);
                float v2 = fmaxf(acc[2], 0.f), v3 = fmaxf(acc[3], 0.f);
                const int lastN = nodeBase + 15 < n ? nodeBase + 15 : n - 1;
                const int g0 = gidx(batch, nodeBase, w64) & 63;
                const int g1 = gidx(batch, lastN, w64) & 63;
                if (nodeBase + 15 < n && g0 == g1) {
                    float cs = v0 + v1 + v2 + v3;
                    cs += __shfl_xor(cs, 16, 64);
                    cs += __shfl_xor(cs, 32, 64);
                    if (quad == 0) atomicAdd(&pool[g0 * 64 + t * 16 + m16], cs);
                } else {  // graph-boundary tile (rare): per-node atomics
                    const float vv[4] = {v0, v1, v2, v3};
#pragma unroll
                    for (int rg = 0; rg < 4; ++rg) {
                        const int node = nodeBase + quad * 4 + rg;
                        if (node < n) {
                            const int g = gidx(batch, node, w64) & 63;
                            atomicAdd(&pool[g * 64 + t * 16 + m16], vv[rg]);
                        }
                    }
                }
            }
        }
    }
}

// ---------- head MLP: out = relu(g@Wc1+bc1)@Wc2 + bc2 ----------
__global__ void head_kernel(const float* __restrict__ pool, const void* __restrict__ batch,
                            const int* __restrict__ flag,
                            const float* __restrict__ Wc1, const float* __restrict__ bc1,
                            const float* __restrict__ Wc2, const float* __restrict__ bc2,
                            float* __restrict__ out, int n) {
    __shared__ float gm[64 * 64];
    __shared__ float am[64 * 32];
    __shared__ int cnts[64];
    const int tid = threadIdx.x;  // 256
    const int w64 = flag[0];
    if (tid < 64) {
        int lo = 0, hi = n;
        while (lo < hi) { int mid = (lo + hi) >> 1; if (gidx(batch, mid, w64) < tid) lo = mid + 1; else hi = mid; }
        int lo2 = 0, hi2 = n;
        int v2 = tid + 1;
        while (lo2 < hi2) { int mid = (lo2 + hi2) >> 1; if (gidx(batch, mid, w64) < v2) lo2 = mid + 1; else hi2 = mid; }
        cnts[tid] = lo2 - lo;
    }
    __syncthreads();
    for (int i = tid; i < 4096; i += 256) {
        int g = i >> 6;
        float c = (float)(cnts[g] > 0 ? cnts[g] : 1);
        gm[i] = pool[i] / c;
    }
    __syncthreads();
    for (int i = tid; i < 64 * 32; i += 256) {
        int g = i >> 5, j = i & 31;
        float acc = bc1[j];
        for (int k = 0; k < 64; ++k) acc += gm[g * 64 + k] * Wc1[k * 32 + j];
        am[i] = acc > 0.f ? acc : 0.f;
    }
    __syncthreads();
    if (tid < 128) {
        int g = tid >> 1, o = tid & 1;
        float acc = bc2[o];
        for (int j = 0; j < 32; ++j) acc += am[g * 32 + j] * Wc2[j * 2 + o];
        out[tid] = acc;
    }
}

extern "C" void kernel_launch(void* const* d_in, const int* in_sizes, int n_in,
                              void* d_out, int out_size, void* d_ws, size_t ws_size,
                              hipStream_t stream) {
    const float* x   = (const float*)d_in[0];
    const void* edge = d_in[1];     // int32 or int64, auto-detected
    const void* batch = d_in[2];
    const float* W1l = (const float*)d_in[3];
    const float* b1  = (const float*)d_in[4];
    const float* W1r = (const float*)d_in[5];
    const float* W2l = (const float*)d_in[6];
    const float* b2  = (const float*)d_in[7];
    const float* W2r = (const float*)d_in[8];
    const float* W3l = (const float*)d_in[9];
    const float* b3  = (const float*)d_in[10];
    const float* W3r = (const float*)d_in[11];
    const float* Wc1 = (const float*)d_in[12];
    const float* bc1 = (const float*)d_in[13];
    const float* Wc2 = (const float*)d_in[14];
    const float* bc2 = (const float*)d_in[15];

    const int n = in_sizes[0] / 64;   // 100000
    const int E = in_sizes[1] / 2;    // 1600000
    const int nb1 = (n + 511) >> 9;   // 196 coarse buckets (requires <= 256)
    const int NS = nb1 * NBLK1;       // scanned histogram length

    char* w = (char*)d_ws;
    size_t o = 0;
    auto take = [&](size_t bytes) -> void* {
        void* p = w + o;
        o = (o + bytes + 511) & ~(size_t)511;
        return p;
    };
    int* flag      = (int*)take(sizeof(int));
    u32* ticket    = (u32*)take(2 * sizeof(u32));
    u32* offs      = (u32*)take((size_t)(n + 1) * sizeof(u32));
    u32* HG        = (u32*)take((size_t)(NS + 1) * sizeof(u32));
    u32* blockSums = (u32*)take(256 * sizeof(u32));
    u32* SB        = (u32*)take(256 * sizeof(u32));
    u32* P         = (u32*)take((size_t)E * sizeof(u32));
    int* ss        = (int*)take((size_t)E * sizeof(int));
    u16* Xh        = (u16*)take((size_t)n * 64 * sizeof(u16));
    u16* HA        = (u16*)take((size_t)n * 64 * sizeof(u16));
    u16* HB        = (u16*)take((size_t)n * 64 * sizeof(u16));
    _Float16* WF   = (_Float16*)take(WPREP * 4096 * sizeof(_Float16));
    float* pool    = (float*)take(64 * 64 * sizeof(float));

    // CSR coarse hist + X->fp16 convert + weight-frag prep in one launch
    fused_hist_cvt<<<NBLK1 + CVTBLK + WPREP, 256, 0, stream>>>(
        edge, flag, ticket, HG, E, n, nb1, x, Xh, W1l, W1r, W2l, W2r, W3l, W3r, WF);
    const int nbScan = (NS + 2047) / 2048;
    scanAB<<<nbScan, 256, 0, stream>>>(HG, blockSums, SB, ticket, NS);
    p1_scatter<<<NBLK1, 256, 0, stream>>>(edge, flag, HG, SB, P, E, n, nb1);
    p2_kernel<<<nb1, 512, 0, stream>>>(P, HG, SB, offs, ss, pool, E, n, nb1);

    const int ntiles = (n + 15) >> 4;
    const int SLBLK = (ntiles + 3) >> 2;   // 1 wave per 16-node tile
    sage3<<<SLBLK, 256, 0, stream>>>(Xh, offs, ss, WF, b1, HA, nullptr,
                                     batch, flag, n, 0);
    sage3<<<SLBLK, 256, 0, stream>>>(HA, offs, ss, WF + 2 * 4096, b2, HB, nullptr,
                                     batch, flag, n, 0);
    sage3<<<SLBLK, 256, 0, stream>>>(HB, offs, ss, WF + 4 * 4096, b3, nullptr, pool,
                                     batch, flag, n, 1);
    head_kernel<<<1, 256, 0, stream>>>(pool, batch, flag, Wc1, bc1, Wc2, bc2,
                                       (float*)d_out, n);
}